// Round 2
// baseline (675.060 us; speedup 1.0000x reference)
//
#include <hip/hip_runtime.h>

typedef unsigned short u16;
typedef __bf16 bf8v __attribute__((ext_vector_type(8)));
typedef float f4v __attribute__((ext_vector_type(4)));
typedef f4v __attribute__((may_alias)) f4va;   // defeat TBAA for LDS/global reinterprets

#define NTOK   49
#define NPAD   64
#define CDIM   96
#define FEAT_  56
#define HWIM   3136
#define SHIFT_ 3

__device__ __forceinline__ float b2f(u16 u) {
  unsigned v = ((unsigned)u) << 16;
  return __builtin_bit_cast(float, v);
}
__device__ __forceinline__ u16 f2b(float f) {   // RNE fp32->bf16
  unsigned u = __builtin_bit_cast(unsigned, f);
  u += 0x7fffu + ((u >> 16) & 1u);
  return (u16)(u >> 16);
}
__device__ __forceinline__ bf8v fragld(const u16* p) {
  return __builtin_bit_cast(bf8v, *(const f4va*)p);   // 16B ds_read_b128
}
// 8 consecutive fp32 -> bf16x8 fragment (for weight B-operands straight from global)
__device__ __forceinline__ bf8v cvt8(const float* p) {
  f4v a = *(const f4va*)p;
  f4v b = *(const f4va*)(p + 4);
  union { u16 u[8]; bf8v v; } r;
#pragma unroll
  for (int j = 0; j < 4; ++j) { r.u[j] = f2b(a[j]); r.u[4 + j] = f2b(b[j]); }
  return r.v;
}
__device__ __forceinline__ f4v mfma16(bf8v a, bf8v b, f4v c) {
  return __builtin_amdgcn_mfma_f32_16x16x32_bf16(a, b, c, 0, 0, 0);
}
// shift-mask region label in shifted-image coords: 0..48 / 49..52 / 53..55
__device__ __forceinline__ int reg3(int g) { return g < 49 ? 0 : (g < 53 ? 1 : 2); }

// One block (256 thr, 4 waves) per window; 8192 blocks.
// fp32 in/out; bf16 only inside (MFMA operands). ~78 KB LDS -> 2 blocks/CU.
__global__ __launch_bounds__(256, 2)
void swin_fused(const float* __restrict__ x,
                const float* __restrict__ lng, const float* __restrict__ lnb,
                const float* __restrict__ qw,  const float* __restrict__ qbv,
                const float* __restrict__ pw,  const float* __restrict__ pbv,
                const float* __restrict__ rel,
                float* __restrict__ out) {
  // lifetimes: xf(p1-2) / qk(p3-4) share; win16(p2-3) / outb(p5-6) share.
  __shared__ union { float xf[NTOK][97]; u16 qk[NPAD][200]; } A;  // qk: 0..95 q*scl, 96..191 k
  __shared__ union { u16 win16[NPAD][104]; u16 outb[NPAD][98]; } Bu;
  __shared__ u16 vt[3][32][72];    // V^T per head: [head][d][token]
  __shared__ u16 Pl[NPAD][72];     // softmax probs (wave-private rows)
  __shared__ u16 att[NPAD][104];   // attn@V, cols 0..95
  __shared__ float gw[CDIM], bwt[CDIM];
  __shared__ float rel_f[507];     // rel_table (169,3)
  __shared__ float pb_f[CDIM];
  __shared__ float qb_f[3 * CDIM];

  const int blk = blockIdx.x;
  const int b   = blk >> 6;
  const int wi  = blk & 63;
  const int whb = wi >> 3, wwb = wi & 7;
  const int tid  = threadIdx.x;
  const int wv   = tid >> 6;
  const int lane = tid & 63;
  const int quad = lane >> 4;
  const int l15  = lane & 15;

  // ---- phase 1: stage x window (shift+partition gather, fp32) + params --------
  {
    int p = lane;                   // token
    if (p < NTOK) {
      int r = p / 7, cw = p - r * 7;
      int h = whb * 7 + r + SHIFT_;  if (h >= FEAT_) h -= FEAT_;   // roll(-3)
      int w = wwb * 7 + cw + SHIFT_; if (w >= FEAT_) w -= FEAT_;
      const float* xp = x + b * CDIM * HWIM + h * FEAT_ + w;
      for (int c = wv; c < CDIM; c += 4)
        A.xf[p][c] = xp[c * HWIM];
    }
    for (int i = tid; i < CDIM; i += 256) {
      gw[i] = lng[i]; bwt[i] = lnb[i]; pb_f[i] = pbv[i];
    }
    for (int i = tid; i < 507; i += 256) rel_f[i] = rel[i];
    for (int i = tid; i < 3 * CDIM; i += 256) qb_f[i] = qbv[i];
  }
  __syncthreads();

  // ---- phase 2: LayerNorm (4 lanes per token, shuffle-reduced fp32 stats) -----
  {
    int p  = wv * 16 + (lane >> 2);   // token 0..63 (rows>=49 -> zeros)
    int cg = lane & 3;                // channel quarter
    float s = 0.f, q = 0.f;
    if (p < NTOK)
      for (int i = 0; i < 24; ++i) {
        float v = A.xf[p][cg * 24 + i]; s += v; q += v * v;
      }
    s += __shfl_xor(s, 1, 64); s += __shfl_xor(s, 2, 64);
    q += __shfl_xor(q, 1, 64); q += __shfl_xor(q, 2, 64);
    float m = s * (1.f / 96.f);
    float r = rsqrtf(q * (1.f / 96.f) - m * m + 1e-5f);
    for (int i = 0; i < 24; ++i) {
      int c = cg * 24 + i;
      float v = (p < NTOK) ? (A.xf[p][c] - m) * r * gw[c] + bwt[c] : 0.f;
      Bu.win16[p][c] = f2b(v);       // rows >=49 zeroed => K-padding is bias-only
    }
  }
  __syncthreads();

  // ---- phase 3: QKV GEMM (64x96)@(96x288), N-split across waves ---------------
  {
    bf8v a[4][3];
    for (int mt = 0; mt < 4; ++mt)
      for (int kt = 0; kt < 3; ++kt)
        a[mt][kt] = fragld(&Bu.win16[mt * 16 + l15][kt * 32 + quad * 8]);
    const float qscale = 0.17677669529663687f;   // 1/sqrt(32)
    for (int nt = wv; nt < 18; nt += 4) {
      int n = nt * 16 + l15;                      // output channel 0..287
      const float* wr = qw + n * CDIM;            // qkv_w row n = B^T column n
      bf8v bf[3];
      for (int kt = 0; kt < 3; ++kt) bf[kt] = cvt8(wr + kt * 32 + quad * 8);
      float bias = qb_f[n];
      for (int mt = 0; mt < 4; ++mt) {
        f4v c = {0.f, 0.f, 0.f, 0.f};
        c = mfma16(a[mt][0], bf[0], c);
        c = mfma16(a[mt][1], bf[1], c);
        c = mfma16(a[mt][2], bf[2], c);
        for (int rg = 0; rg < 4; ++rg) {
          int m = mt * 16 + quad * 4 + rg;
          float v = c[rg] + bias;
          if (n < 96)        A.qk[m][n] = f2b(v * qscale);
          else if (n < 192)  A.qk[m][n] = f2b(v);
          else               vt[(n - 192) >> 5][(n - 192) & 31][m] = f2b(v);
        }
      }
    }
  }
  __syncthreads();

  // ---- phase 4: attention per head; wave owns rows [16wv,16wv+16) -------------
  {
    const int rbase = wv * 16 + quad * 4;
    int rcnt[4], ri_[4], ci_[4];
    for (int rg = 0; rg < 4; ++rg) {
      int r = rbase + rg; if (r > 48) r = 48;     // clamp pad rows (output unused)
      int ri = r / 7, ci = r - ri * 7;
      ri_[rg] = ri; ci_[rg] = ci;
      rcnt[rg] = reg3(whb * 7 + ri) * 3 + reg3(wwb * 7 + ci);
    }
    for (int h = 0; h < 3; ++h) {
      bf8v aq = fragld(&A.qk[wv * 16 + l15][h * 32 + quad * 8]);
      f4v S[4];
      for (int nt = 0; nt < 4; ++nt) {
        bf8v bk = fragld(&A.qk[nt * 16 + l15][96 + h * 32 + quad * 8]);
        f4v z = {0.f, 0.f, 0.f, 0.f};
        S[nt] = mfma16(aq, bk, z);                // S = (q*scl) . k
      }
      for (int nt = 0; nt < 4; ++nt) {            // +bias +shift-mask; kill pad cols
        int j = nt * 16 + l15;
        if (j < NTOK) {
          int rj = j / 7, cj = j - rj * 7;
          int jcnt = reg3(whb * 7 + rj) * 3 + reg3(wwb * 7 + cj);
          for (int rg = 0; rg < 4; ++rg) {
            float add = rel_f[((ri_[rg] - rj + 6) * 13 + (ci_[rg] - cj + 6)) * 3 + h];
            if (jcnt != rcnt[rg]) add -= 100.f;
            S[nt][rg] += add;
          }
        } else {
          for (int rg = 0; rg < 4; ++rg) S[nt][rg] = -1e30f;
        }
      }
      float inv[4];                               // row softmax, 16-lane reduce
      for (int rg = 0; rg < 4; ++rg) {
        float m = fmaxf(fmaxf(S[0][rg], S[1][rg]), fmaxf(S[2][rg], S[3][rg]));
        for (int off = 1; off < 16; off <<= 1) m = fmaxf(m, __shfl_xor(m, off, 64));
        float s = 0.f;
        for (int nt = 0; nt < 4; ++nt) {
          float e = __expf(S[nt][rg] - m); S[nt][rg] = e; s += e;
        }
        for (int off = 1; off < 16; off <<= 1) s += __shfl_xor(s, off, 64);
        inv[rg] = 1.f / s;
      }
      for (int nt = 0; nt < 4; ++nt) {
        int j = nt * 16 + l15;
        for (int rg = 0; rg < 4; ++rg)
          Pl[rbase + rg][j] = f2b(S[nt][rg] * inv[rg]);   // pad cols underflow to 0
      }
      // P@V (K=64 tokens); wave reads only its own P rows -> no barrier
      bf8v ap0 = fragld(&Pl[wv * 16 + l15][quad * 8]);
      bf8v ap1 = fragld(&Pl[wv * 16 + l15][32 + quad * 8]);
      for (int nt = 0; nt < 2; ++nt) {
        bf8v bv0 = fragld(&vt[h][nt * 16 + l15][quad * 8]);
        bf8v bv1 = fragld(&vt[h][nt * 16 + l15][32 + quad * 8]);
        f4v c = {0.f, 0.f, 0.f, 0.f};
        c = mfma16(ap0, bv0, c);
        c = mfma16(ap1, bv1, c);
        for (int rg = 0; rg < 4; ++rg)
          att[rbase + rg][h * 32 + nt * 16 + l15] = f2b(c[rg]);
      }
    }
  }
  __syncthreads();

  // ---- phase 5: proj GEMM (64x96)@(96x96), N-split ----------------------------
  {
    bf8v a[4][3];
    for (int mt = 0; mt < 4; ++mt)
      for (int kt = 0; kt < 3; ++kt)
        a[mt][kt] = fragld(&att[mt * 16 + l15][kt * 32 + quad * 8]);
    for (int nt = wv; nt < 6; nt += 4) {
      int n = nt * 16 + l15;
      const float* wr = pw + n * CDIM;
      bf8v bf[3];
      for (int kt = 0; kt < 3; ++kt) bf[kt] = cvt8(wr + kt * 32 + quad * 8);
      float bias = pb_f[n];
      for (int mt = 0; mt < 4; ++mt) {
        f4v c = {0.f, 0.f, 0.f, 0.f};
        c = mfma16(a[mt][0], bf[0], c);
        c = mfma16(a[mt][1], bf[1], c);
        c = mfma16(a[mt][2], bf[2], c);
        for (int rg = 0; rg < 4; ++rg)
          Bu.outb[mt * 16 + quad * 4 + rg][n] = f2b(c[rg] + bias);
      }
    }
  }
  __syncthreads();

  // ---- phase 6: window-reverse + unshift scatter (fp32 stores) ----------------
  {
    int p = lane;
    if (p < NTOK) {
      int r = p / 7, cw = p - r * 7;
      int h = whb * 7 + r + SHIFT_;  if (h >= FEAT_) h -= FEAT_;
      int w = wwb * 7 + cw + SHIFT_; if (w >= FEAT_) w -= FEAT_;
      float* op = out + b * CDIM * HWIM + h * FEAT_ + w;
      for (int c = wv; c < CDIM; c += 4)
        op[c * HWIM] = b2f(Bu.outb[p][c]);
    }
  }
}

extern "C" void kernel_launch(void* const* d_in, const int* in_sizes, int n_in,
                              void* d_out, int out_size, void* d_ws, size_t ws_size,
                              hipStream_t stream) {
  (void)in_sizes; (void)n_in; (void)out_size; (void)d_ws; (void)ws_size;
  const float* x   = (const float*)d_in[0];
  const float* lng = (const float*)d_in[1];
  const float* lnb = (const float*)d_in[2];
  const float* qw  = (const float*)d_in[3];
  const float* qbv = (const float*)d_in[4];
  const float* pw  = (const float*)d_in[5];
  const float* pbv = (const float*)d_in[6];
  const float* rel = (const float*)d_in[7];
  float* out = (float*)d_out;
  swin_fused<<<dim3(8192), dim3(256), 0, stream>>>(x, lng, lnb, qw, qbv, pw, pbv, rel, out);
}

// Round 3
// 558.665 us; speedup vs baseline: 1.2083x; 1.2083x over previous
//
#include <hip/hip_runtime.h>

typedef unsigned short u16;
typedef __bf16 bf8v __attribute__((ext_vector_type(8)));
typedef float f4v __attribute__((ext_vector_type(4)));
typedef f4v __attribute__((may_alias)) f4va;   // defeat TBAA for LDS/global reinterprets

#define NTOK   49
#define NPAD   64
#define CDIM   96
#define FEAT_  56
#define HWIM   3136
#define SHIFT_ 3

// workspace layout (u16 units)
#define WIN_ELEMS (128 * 64 * 49 * 96)          // 38,535,168 u16 = 77.07 MB
#define QW_ELEMS  (288 * 96)                    // 27,648
#define PW_ELEMS  (96 * 96)                     // 9,216
#define WS_NEEDED ((size_t)(WIN_ELEMS + QW_ELEMS + PW_ELEMS) * 2)

__device__ __forceinline__ float b2f(u16 u) {
  unsigned v = ((unsigned)u) << 16;
  return __builtin_bit_cast(float, v);
}
__device__ __forceinline__ u16 f2b(float f) {   // RNE fp32->bf16
  unsigned u = __builtin_bit_cast(unsigned, f);
  u += 0x7fffu + ((u >> 16) & 1u);
  return (u16)(u >> 16);
}
__device__ __forceinline__ bf8v fragld(const u16* p) {
  return __builtin_bit_cast(bf8v, *(const f4va*)p);   // 16B b128 load
}
__device__ __forceinline__ bf8v cvt8(const float* p) {
  f4v a = *(const f4va*)p;
  f4v b = *(const f4va*)(p + 4);
  union { u16 u[8]; bf8v v; } r;
#pragma unroll
  for (int j = 0; j < 4; ++j) { r.u[j] = f2b(a[j]); r.u[4 + j] = f2b(b[j]); }
  return r.v;
}
__device__ __forceinline__ f4v mfma16(bf8v a, bf8v b, f4v c) {
  return __builtin_amdgcn_mfma_f32_16x16x32_bf16(a, b, c, 0, 0, 0);
}
__device__ __forceinline__ int reg3(int g) { return g < 49 ? 0 : (g < 53 ? 1 : 2); }

// ---- K0: weights fp32 -> bf16 (once per call) --------------------------------
__global__ __launch_bounds__(256)
void swin_wcvt(const float* __restrict__ qw, const float* __restrict__ pw,
               u16* __restrict__ qwb, u16* __restrict__ pwb) {
  int i = blockIdx.x * 256 + threadIdx.x;        // 36864 threads exactly
  if (i < QW_ELEMS) qwb[i] = f2b(qw[i]);
  else              pwb[i - QW_ELEMS] = f2b(pw[i - QW_ELEMS]);
}

// ---- K1: LN + shift + window-partition + bf16 pack. block=(b,hs) -------------
__global__ __launch_bounds__(256, 4)
void swin_ln_pack(const float* __restrict__ x,
                  const float* __restrict__ lng, const float* __restrict__ lnb,
                  u16* __restrict__ winbuf) {
  __shared__ float xf[CDIM][57];     // [c][ws], stride 57: conflict-free lanes=ws
  __shared__ u16 wtile[FEAT_][104];  // [ws][c], stride 104 (16B-aligned rows)
  __shared__ float ps[4][64], pq[4][64];
  __shared__ float gw[CDIM], bw[CDIM];

  const int bid = blockIdx.x;
  const int b = bid / FEAT_, hs = bid - b * FEAT_;   // shifted row
  int h = hs + SHIFT_; if (h >= FEAT_) h -= FEAT_;   // source row
  const int tid = threadIdx.x, wv = tid >> 6, lane = tid & 63;

  for (int i = tid; i < CDIM; i += 256) { gw[i] = lng[i]; bw[i] = lnb[i]; }

  float s = 0.f, q = 0.f;
  const int ws = lane;
  int wsrc = ws + SHIFT_; if (wsrc >= FEAT_) wsrc -= FEAT_;
  const float* base = x + (size_t)b * CDIM * HWIM + h * FEAT_;
  if (ws < FEAT_)
    for (int i = 0; i < 24; ++i) {                   // wave owns channel quarter
      int c = wv * 24 + i;
      float v = base[c * HWIM + wsrc];               // contiguous 224B runs/instr
      xf[c][ws] = v; s += v; q += v * v;
    }
  ps[wv][lane] = s; pq[wv][lane] = q;
  __syncthreads();
  if (ws < FEAT_) {
    float ts = ps[0][ws] + ps[1][ws] + ps[2][ws] + ps[3][ws];
    float tq = pq[0][ws] + pq[1][ws] + pq[2][ws] + pq[3][ws];
    float m = ts * (1.f / 96.f);
    float r = rsqrtf(tq * (1.f / 96.f) - m * m + 1e-5f);
    for (int i = 0; i < 24; ++i) {
      int c = wv * 24 + i;
      wtile[ws][c] = f2b((xf[c][ws] - m) * r * gw[c] + bw[c]);
    }
  }
  __syncthreads();
  // write 8 windows x 672 u16 contiguous runs (1344 B each), 16B chunks
  const int wrow = hs / 7, tr = hs - wrow * 7;
  for (int idx = tid; idx < 672; idx += 256) {
    int ww = idx / 84, r = idx - ww * 84;
    int wl = r / 12, cc = r - wl * 12;
    u16* dst = winbuf + ((size_t)((b * 64 + wrow * 8 + ww) * 49 + tr * 7)) * CDIM + r * 8;
    *(f4va*)dst = *(const f4va*)&wtile[ww * 7 + wl][cc * 8];
  }
}

// ---- K2: fused window attention (QKV -> attn -> proj), in-place on winbuf ----
__global__ __launch_bounds__(256, 2)
void swin_attn(u16* __restrict__ winbuf,
               const u16* __restrict__ qwb, const u16* __restrict__ pwb,
               const float* __restrict__ qbv, const float* __restrict__ pbv,
               const float* __restrict__ rel) {
  __shared__ u16 wio[NPAD][104];   // in: LN'd window tokens; out: proj result
  __shared__ u16 qk[NPAD][200];    // 0..95 q*scale, 96..191 k
  __shared__ u16 vt[3][32][72];    // V^T per head [head][d][token]
  __shared__ u16 Pl[NPAD][72];     // probs (wave-private rows)
  __shared__ u16 att[NPAD][104];   // attn@V, cols 0..95
  __shared__ float rel_f[507];
  __shared__ float pb_f[CDIM];
  __shared__ float qb_f[3 * CDIM];

  const int blk = blockIdx.x;
  const int wi = blk & 63;
  const int whb = wi >> 3, wwb = wi & 7;
  const int tid = threadIdx.x;
  const int wv = tid >> 6, lane = tid & 63;
  const int quad = lane >> 4, l15 = lane & 15;

  u16* wbase = winbuf + (size_t)blk * (NTOK * CDIM);

  // ---- phase 1: contiguous coop load (9408 B) + zero pad rows + params -------
  for (int idx = tid; idx < 588; idx += 256) {
    int row = idx / 12, cc = idx - row * 12;
    *(f4va*)&wio[row][cc * 8] = *(const f4va*)(wbase + idx * 8);
  }
  {
    f4v z = {0.f, 0.f, 0.f, 0.f};
    for (int idx = tid; idx < 180; idx += 256) {    // rows 49..63, cols 0..95
      int row = 49 + idx / 12, cc = idx - (idx / 12) * 12;
      *(f4va*)&wio[row][cc * 8] = z;
    }
  }
  for (int i = tid; i < 507; i += 256) rel_f[i] = rel[i];
  for (int i = tid; i < 3 * CDIM; i += 256) qb_f[i] = qbv[i];
  for (int i = tid; i < CDIM; i += 256) pb_f[i] = pbv[i];
  __syncthreads();

  // ---- phase 3: QKV GEMM (64x96)@(96x288), N-split across waves --------------
  {
    bf8v a[4][3];
    for (int mt = 0; mt < 4; ++mt)
      for (int kt = 0; kt < 3; ++kt)
        a[mt][kt] = fragld(&wio[mt * 16 + l15][kt * 32 + quad * 8]);
    const float qscale = 0.17677669529663687f;      // 1/sqrt(32)
    for (int nt = wv; nt < 18; nt += 4) {
      int n = nt * 16 + l15;
      bf8v bf[3];
      for (int kt = 0; kt < 3; ++kt)
        bf[kt] = fragld(qwb + n * CDIM + kt * 32 + quad * 8);
      float bias = qb_f[n];
      for (int mt = 0; mt < 4; ++mt) {
        f4v c = {0.f, 0.f, 0.f, 0.f};
        c = mfma16(a[mt][0], bf[0], c);
        c = mfma16(a[mt][1], bf[1], c);
        c = mfma16(a[mt][2], bf[2], c);
        for (int rg = 0; rg < 4; ++rg) {
          int m = mt * 16 + quad * 4 + rg;
          float v = c[rg] + bias;
          if (n < 96)        qk[m][n] = f2b(v * qscale);
          else if (n < 192)  qk[m][n] = f2b(v);
          else               vt[(n - 192) >> 5][(n - 192) & 31][m] = f2b(v);
        }
      }
    }
  }
  __syncthreads();

  // ---- phase 4: attention per head; wave owns rows [16wv,16wv+16) ------------
  {
    const int rbase = wv * 16 + quad * 4;
    int rcnt[4], ri_[4], ci_[4];
    for (int rg = 0; rg < 4; ++rg) {
      int r = rbase + rg; if (r > 48) r = 48;
      int ri = r / 7, ci = r - ri * 7;
      ri_[rg] = ri; ci_[rg] = ci;
      rcnt[rg] = reg3(whb * 7 + ri) * 3 + reg3(wwb * 7 + ci);
    }
    for (int h = 0; h < 3; ++h) {
      bf8v aq = fragld(&qk[wv * 16 + l15][h * 32 + quad * 8]);
      f4v S[4];
      for (int nt = 0; nt < 4; ++nt) {
        bf8v bk = fragld(&qk[nt * 16 + l15][96 + h * 32 + quad * 8]);
        f4v z = {0.f, 0.f, 0.f, 0.f};
        S[nt] = mfma16(aq, bk, z);
      }
      for (int nt = 0; nt < 4; ++nt) {
        int j = nt * 16 + l15;
        if (j < NTOK) {
          int rj = j / 7, cj = j - rj * 7;
          int jcnt = reg3(whb * 7 + rj) * 3 + reg3(wwb * 7 + cj);
          for (int rg = 0; rg < 4; ++rg) {
            float add = rel_f[((ri_[rg] - rj + 6) * 13 + (ci_[rg] - cj + 6)) * 3 + h];
            if (jcnt != rcnt[rg]) add -= 100.f;
            S[nt][rg] += add;
          }
        } else {
          for (int rg = 0; rg < 4; ++rg) S[nt][rg] = -1e30f;
        }
      }
      float inv[4];
      for (int rg = 0; rg < 4; ++rg) {
        float m = fmaxf(fmaxf(S[0][rg], S[1][rg]), fmaxf(S[2][rg], S[3][rg]));
        for (int off = 1; off < 16; off <<= 1) m = fmaxf(m, __shfl_xor(m, off, 64));
        float s = 0.f;
        for (int nt = 0; nt < 4; ++nt) {
          float e = __expf(S[nt][rg] - m); S[nt][rg] = e; s += e;
        }
        for (int off = 1; off < 16; off <<= 1) s += __shfl_xor(s, off, 64);
        inv[rg] = 1.f / s;
      }
      for (int nt = 0; nt < 4; ++nt) {
        int j = nt * 16 + l15;
        for (int rg = 0; rg < 4; ++rg)
          Pl[rbase + rg][j] = f2b(S[nt][rg] * inv[rg]);
      }
      bf8v ap0 = fragld(&Pl[wv * 16 + l15][quad * 8]);
      bf8v ap1 = fragld(&Pl[wv * 16 + l15][32 + quad * 8]);
      for (int nt = 0; nt < 2; ++nt) {
        bf8v bv0 = fragld(&vt[h][nt * 16 + l15][quad * 8]);
        bf8v bv1 = fragld(&vt[h][nt * 16 + l15][32 + quad * 8]);
        f4v c = {0.f, 0.f, 0.f, 0.f};
        c = mfma16(ap0, bv0, c);
        c = mfma16(ap1, bv1, c);
        for (int rg = 0; rg < 4; ++rg)
          att[rbase + rg][h * 32 + nt * 16 + l15] = f2b(c[rg]);
      }
    }
  }
  __syncthreads();

  // ---- phase 5: proj GEMM (64x96)@(96x96) -> wio (overwrites input tile) -----
  {
    bf8v a[4][3];
    for (int mt = 0; mt < 4; ++mt)
      for (int kt = 0; kt < 3; ++kt)
        a[mt][kt] = fragld(&att[mt * 16 + l15][kt * 32 + quad * 8]);
    for (int nt = wv; nt < 6; nt += 4) {
      int n = nt * 16 + l15;
      bf8v bf[3];
      for (int kt = 0; kt < 3; ++kt)
        bf[kt] = fragld(pwb + n * CDIM + kt * 32 + quad * 8);
      float bias = pb_f[n];
      for (int mt = 0; mt < 4; ++mt) {
        f4v c = {0.f, 0.f, 0.f, 0.f};
        c = mfma16(a[mt][0], bf[0], c);
        c = mfma16(a[mt][1], bf[1], c);
        c = mfma16(a[mt][2], bf[2], c);
        for (int rg = 0; rg < 4; ++rg)
          wio[mt * 16 + quad * 4 + rg][n] = f2b(c[rg] + bias);
      }
    }
  }
  __syncthreads();

  // ---- phase 6: contiguous coop store (in-place over this block's window) ----
  for (int idx = tid; idx < 588; idx += 256) {
    int row = idx / 12, cc = idx - row * 12;
    *(f4va*)(wbase + idx * 8) = *(const f4va*)&wio[row][cc * 8];
  }
}

// ---- K3: window-reverse + unshift + bf16->fp32 transpose. block=(b,h) --------
__global__ __launch_bounds__(256, 4)
void swin_unpack(const u16* __restrict__ winbuf, float* __restrict__ out) {
  __shared__ u16 wtile[FEAT_][104];   // [w][c]
  const int bid = blockIdx.x;
  const int b = bid / FEAT_, h = bid - b * FEAT_;
  int hs = h - SHIFT_; if (hs < 0) hs += FEAT_;
  const int wrow = hs / 7, tr = hs - wrow * 7;
  const int tid = threadIdx.x, wv = tid >> 6, lane = tid & 63;

  for (int idx = tid; idx < 672; idx += 256) {
    int ww = idx / 84, r = idx - ww * 84;
    const u16* src = winbuf + ((size_t)((b * 64 + wrow * 8 + ww) * 49 + tr * 7)) * CDIM + r * 8;
    int wl = r / 12, cc = r - wl * 12;
    int ws = ww * 7 + wl;
    int w = ws + SHIFT_; if (w >= FEAT_) w -= FEAT_;
    *(f4va*)&wtile[w][cc * 8] = *(const f4va*)src;
  }
  __syncthreads();
  if (lane < FEAT_) {
    float* obase = out + (size_t)b * CDIM * HWIM + h * FEAT_ + lane;
    for (int i = 0; i < 24; ++i) {
      int c = wv * 24 + i;
      obase[c * HWIM] = b2f(wtile[lane][c]);   // contiguous 224B stores/instr
    }
  }
}

// ---- fallback: round-2 monolithic kernel (used if ws too small) --------------
__global__ __launch_bounds__(256, 2)
void swin_fused_fb(const float* __restrict__ x,
                   const float* __restrict__ lng, const float* __restrict__ lnb,
                   const float* __restrict__ qw,  const float* __restrict__ qbv,
                   const float* __restrict__ pw,  const float* __restrict__ pbv,
                   const float* __restrict__ rel,
                   float* __restrict__ out) {
  __shared__ union { float xf[NTOK][97]; u16 qk[NPAD][200]; } A;
  __shared__ union { u16 win16[NPAD][104]; u16 outb[NPAD][98]; } Bu;
  __shared__ u16 vt[3][32][72];
  __shared__ u16 Pl[NPAD][72];
  __shared__ u16 att[NPAD][104];
  __shared__ float gw[CDIM], bwt[CDIM];
  __shared__ float rel_f[507];
  __shared__ float pb_f[CDIM];
  __shared__ float qb_f[3 * CDIM];

  const int blk = blockIdx.x;
  const int b = blk >> 6, wi = blk & 63;
  const int whb = wi >> 3, wwb = wi & 7;
  const int tid = threadIdx.x, wv = tid >> 6, lane = tid & 63;
  const int quad = lane >> 4, l15 = lane & 15;
  {
    int p = lane;
    if (p < NTOK) {
      int r = p / 7, cw = p - r * 7;
      int h = whb * 7 + r + SHIFT_;  if (h >= FEAT_) h -= FEAT_;
      int w = wwb * 7 + cw + SHIFT_; if (w >= FEAT_) w -= FEAT_;
      const float* xp = x + b * CDIM * HWIM + h * FEAT_ + w;
      for (int c = wv; c < CDIM; c += 4) A.xf[p][c] = xp[c * HWIM];
    }
    for (int i = tid; i < CDIM; i += 256) { gw[i] = lng[i]; bwt[i] = lnb[i]; pb_f[i] = pbv[i]; }
    for (int i = tid; i < 507; i += 256) rel_f[i] = rel[i];
    for (int i = tid; i < 3 * CDIM; i += 256) qb_f[i] = qbv[i];
  }
  __syncthreads();
  {
    int p = wv * 16 + (lane >> 2), cg = lane & 3;
    float s = 0.f, q = 0.f;
    if (p < NTOK)
      for (int i = 0; i < 24; ++i) { float v = A.xf[p][cg * 24 + i]; s += v; q += v * v; }
    s += __shfl_xor(s, 1, 64); s += __shfl_xor(s, 2, 64);
    q += __shfl_xor(q, 1, 64); q += __shfl_xor(q, 2, 64);
    float m = s * (1.f / 96.f);
    float r = rsqrtf(q * (1.f / 96.f) - m * m + 1e-5f);
    for (int i = 0; i < 24; ++i) {
      int c = cg * 24 + i;
      float v = (p < NTOK) ? (A.xf[p][c] - m) * r * gw[c] + bwt[c] : 0.f;
      Bu.win16[p][c] = f2b(v);
    }
  }
  __syncthreads();
  {
    bf8v a[4][3];
    for (int mt = 0; mt < 4; ++mt)
      for (int kt = 0; kt < 3; ++kt)
        a[mt][kt] = fragld(&Bu.win16[mt * 16 + l15][kt * 32 + quad * 8]);
    const float qscale = 0.17677669529663687f;
    for (int nt = wv; nt < 18; nt += 4) {
      int n = nt * 16 + l15;
      const float* wr = qw + n * CDIM;
      bf8v bf[3];
      for (int kt = 0; kt < 3; ++kt) bf[kt] = cvt8(wr + kt * 32 + quad * 8);
      float bias = qb_f[n];
      for (int mt = 0; mt < 4; ++mt) {
        f4v c = {0.f, 0.f, 0.f, 0.f};
        c = mfma16(a[mt][0], bf[0], c);
        c = mfma16(a[mt][1], bf[1], c);
        c = mfma16(a[mt][2], bf[2], c);
        for (int rg = 0; rg < 4; ++rg) {
          int m = mt * 16 + quad * 4 + rg;
          float v = c[rg] + bias;
          if (n < 96)        A.qk[m][n] = f2b(v * qscale);
          else if (n < 192)  A.qk[m][n] = f2b(v);
          else               vt[(n - 192) >> 5][(n - 192) & 31][m] = f2b(v);
        }
      }
    }
  }
  __syncthreads();
  {
    const int rbase = wv * 16 + quad * 4;
    int rcnt[4], ri_[4], ci_[4];
    for (int rg = 0; rg < 4; ++rg) {
      int r = rbase + rg; if (r > 48) r = 48;
      int ri = r / 7, ci = r - ri * 7;
      ri_[rg] = ri; ci_[rg] = ci;
      rcnt[rg] = reg3(whb * 7 + ri) * 3 + reg3(wwb * 7 + ci);
    }
    for (int h = 0; h < 3; ++h) {
      bf8v aq = fragld(&A.qk[wv * 16 + l15][h * 32 + quad * 8]);
      f4v S[4];
      for (int nt = 0; nt < 4; ++nt) {
        bf8v bk = fragld(&A.qk[nt * 16 + l15][96 + h * 32 + quad * 8]);
        f4v z = {0.f, 0.f, 0.f, 0.f};
        S[nt] = mfma16(aq, bk, z);
      }
      for (int nt = 0; nt < 4; ++nt) {
        int j = nt * 16 + l15;
        if (j < NTOK) {
          int rj = j / 7, cj = j - rj * 7;
          int jcnt = reg3(whb * 7 + rj) * 3 + reg3(wwb * 7 + cj);
          for (int rg = 0; rg < 4; ++rg) {
            float add = rel_f[((ri_[rg] - rj + 6) * 13 + (ci_[rg] - cj + 6)) * 3 + h];
            if (jcnt != rcnt[rg]) add -= 100.f;
            S[nt][rg] += add;
          }
        } else {
          for (int rg = 0; rg < 4; ++rg) S[nt][rg] = -1e30f;
        }
      }
      float inv[4];
      for (int rg = 0; rg < 4; ++rg) {
        float m = fmaxf(fmaxf(S[0][rg], S[1][rg]), fmaxf(S[2][rg], S[3][rg]));
        for (int off = 1; off < 16; off <<= 1) m = fmaxf(m, __shfl_xor(m, off, 64));
        float s = 0.f;
        for (int nt = 0; nt < 4; ++nt) { float e = __expf(S[nt][rg] - m); S[nt][rg] = e; s += e; }
        for (int off = 1; off < 16; off <<= 1) s += __shfl_xor(s, off, 64);
        inv[rg] = 1.f / s;
      }
      for (int nt = 0; nt < 4; ++nt) {
        int j = nt * 16 + l15;
        for (int rg = 0; rg < 4; ++rg) Pl[rbase + rg][j] = f2b(S[nt][rg] * inv[rg]);
      }
      bf8v ap0 = fragld(&Pl[wv * 16 + l15][quad * 8]);
      bf8v ap1 = fragld(&Pl[wv * 16 + l15][32 + quad * 8]);
      for (int nt = 0; nt < 2; ++nt) {
        bf8v bv0 = fragld(&vt[h][nt * 16 + l15][quad * 8]);
        bf8v bv1 = fragld(&vt[h][nt * 16 + l15][32 + quad * 8]);
        f4v c = {0.f, 0.f, 0.f, 0.f};
        c = mfma16(ap0, bv0, c);
        c = mfma16(ap1, bv1, c);
        for (int rg = 0; rg < 4; ++rg)
          att[rbase + rg][h * 32 + nt * 16 + l15] = f2b(c[rg]);
      }
    }
  }
  __syncthreads();
  {
    bf8v a[4][3];
    for (int mt = 0; mt < 4; ++mt)
      for (int kt = 0; kt < 3; ++kt)
        a[mt][kt] = fragld(&att[mt * 16 + l15][kt * 32 + quad * 8]);
    for (int nt = wv; nt < 6; nt += 4) {
      int n = nt * 16 + l15;
      const float* wr = pw + n * CDIM;
      bf8v bf[3];
      for (int kt = 0; kt < 3; ++kt) bf[kt] = cvt8(wr + kt * 32 + quad * 8);
      float bias = pb_f[n];
      for (int mt = 0; mt < 4; ++mt) {
        f4v c = {0.f, 0.f, 0.f, 0.f};
        c = mfma16(a[mt][0], bf[0], c);
        c = mfma16(a[mt][1], bf[1], c);
        c = mfma16(a[mt][2], bf[2], c);
        for (int rg = 0; rg < 4; ++rg)
          Bu.outb[mt * 16 + quad * 4 + rg][n] = f2b(c[rg] + bias);
      }
    }
  }
  __syncthreads();
  {
    int p = lane;
    if (p < NTOK) {
      int r = p / 7, cw = p - r * 7;
      int h = whb * 7 + r + SHIFT_;  if (h >= FEAT_) h -= FEAT_;
      int w = wwb * 7 + cw + SHIFT_; if (w >= FEAT_) w -= FEAT_;
      float* op = out + b * CDIM * HWIM + h * FEAT_ + w;
      for (int c = wv; c < CDIM; c += 4) op[c * HWIM] = b2f(Bu.outb[p][c]);
    }
  }
}

extern "C" void kernel_launch(void* const* d_in, const int* in_sizes, int n_in,
                              void* d_out, int out_size, void* d_ws, size_t ws_size,
                              hipStream_t stream) {
  (void)in_sizes; (void)n_in; (void)out_size;
  const float* x   = (const float*)d_in[0];
  const float* lng = (const float*)d_in[1];
  const float* lnb = (const float*)d_in[2];
  const float* qw  = (const float*)d_in[3];
  const float* qbv = (const float*)d_in[4];
  const float* pw  = (const float*)d_in[5];
  const float* pbv = (const float*)d_in[6];
  const float* rel = (const float*)d_in[7];
  float* out = (float*)d_out;

  if (ws_size >= WS_NEEDED) {
    u16* winbuf = (u16*)d_ws;
    u16* qwb = winbuf + WIN_ELEMS;
    u16* pwb = qwb + QW_ELEMS;
    swin_wcvt<<<dim3(144), dim3(256), 0, stream>>>(qw, pw, qwb, pwb);
    swin_ln_pack<<<dim3(128 * FEAT_), dim3(256), 0, stream>>>(x, lng, lnb, winbuf);
    swin_attn<<<dim3(8192), dim3(256), 0, stream>>>(winbuf, qwb, pwb, qbv, pbv, rel);
    swin_unpack<<<dim3(128 * FEAT_), dim3(256), 0, stream>>>(winbuf, out);
  } else {
    swin_fused_fb<<<dim3(8192), dim3(256), 0, stream>>>(x, lng, lnb, qw, qbv, pw, pbv, rel, out);
  }
}